// Round 1
// baseline (182.822 us; speedup 1.0000x reference)
//
#include <hip/hip_runtime.h>
#include <math.h>

#define Bn 2
#define Ln 256
#define Hn 256
#define Cn 5

typedef _Float16 half8 __attribute__((ext_vector_type(8)));
typedef _Float16 half2v __attribute__((ext_vector_type(2)));
typedef _Float16 half4v __attribute__((ext_vector_type(4)));
typedef float floatx4 __attribute__((ext_vector_type(4)));

// ---------------------------------------------------------------------------
// Prep kernel (one launch, blockIdx branches):
//  [0,255):    R[d][h]  = sum_k table[d][k] * Wh_w[k][h]        (255x256 f32)
//  [255,319):  a[r][h]  = hs[r]@(We+Wd) + Wh_b ; bv[r][h] = hs[r]@(Ws-Wd)
//  [319,383):  WmT chunk-major f16: WmT[(kc*256+h)*64 + kk] = Wm[kc*64+kk][h]
// ---------------------------------------------------------------------------
__global__ __launch_bounds__(256) void k_prep(
    const float* __restrict__ hs, const float* __restrict__ Wh,
    const float* __restrict__ Whb,
    float* __restrict__ R, float* __restrict__ a, float* __restrict__ bv,
    _Float16* __restrict__ WmT)
{
  __shared__ float smem[2048];
  int bid = blockIdx.x, tid = threadIdx.x;
  if (bid < 255) {
    int d = bid;
    for (int k = tid; k < 1024; k += 256) {
      float e = (float)(k & ~1) * (1.0f / 1024.f);
      float dv = powf(10000.f, e);
      float ang = (float)d / dv;
      smem[k] = (k & 1) ? cosf(ang) : sinf(ang);
    }
    __syncthreads();
    float acc = 0.f;
    for (int k = 0; k < 1024; ++k) acc = fmaf(smem[k], Wh[k * Hn + tid], acc);
    R[d * Hn + tid] = acc;
  } else if (bid < 319) {
    int r0 = (bid - 255) * 8;  // 8 rows of [B*L] per block
    for (int idx = tid; idx < 2048; idx += 256) smem[idx] = hs[r0 * Hn + idx];
    __syncthreads();
    int h = tid;
    float aa[8] = {0, 0, 0, 0, 0, 0, 0, 0}, bb[8] = {0, 0, 0, 0, 0, 0, 0, 0};
    for (int k = 0; k < 256; ++k) {
      float we = Wh[k * Hn + h];
      float wsv = Wh[(256 + k) * Hn + h];
      float wd = Wh[(512 + k) * Hn + h];
      float wA = we + wd, wB = wsv - wd;
#pragma unroll
      for (int r = 0; r < 8; ++r) {
        float x = smem[r * 256 + k];
        aa[r] = fmaf(x, wA, aa[r]);
        bb[r] = fmaf(x, wB, bb[r]);
      }
    }
    float bias = Whb[h];
#pragma unroll
    for (int r = 0; r < 8; ++r) {
      a[(r0 + r) * Hn + h] = aa[r] + bias;
      bv[(r0 + r) * Hn + h] = bb[r];
    }
  } else {
    int t = (bid - 319) * 256 + tid;  // 0..16383, 4 k-elements each
    int h = t >> 6;
    int k4 = (t & 63) * 4;
    half4v v;
#pragma unroll
    for (int q = 0; q < 4; ++q) v[q] = (_Float16)Wh[(768 + k4 + q) * Hn + h];
    int kc = k4 >> 6, kk = k4 & 63;
    *(half4v*)(WmT + ((kc * 256 + h) * 64 + kk)) = v;
  }
}

// ---------------------------------------------------------------------------
// Main kernel: block = (b, i, j-tile of 64). 4 waves; wave w owns h' in
// [w*64,(w+1)*64), all 64 j  ->  4x4 tiles of mfma_f32_16x16x32_f16.
//   pre[j,h'] = (x_i . x_j) @ Wm  + a_i[h'](init, incl bias) + bv[j,h'] + R[d,h']
//   out[b,c,i,j] = sum_h' tanh(pre) * Wo[h',c] + Wo_b[c]  (then mask / -tril*1e12)
// ---------------------------------------------------------------------------
__global__ __launch_bounds__(256, 2) void k_main(
    const float* __restrict__ hs, const int* __restrict__ mask,
    const float* __restrict__ R, const float* __restrict__ a,
    const float* __restrict__ bvec, const _Float16* __restrict__ WmT,
    const float* __restrict__ Wo, const float* __restrict__ Wob,
    float* __restrict__ out)
{
  __shared__ __align__(16) _Float16 As[64][264];   // A tile, +8 pad
  __shared__ __align__(16) _Float16 Ws_[256][72];  // W^T k-chunk, +8 pad
  __shared__ float red[4][64][8];                  // cross-wave C partials

  int bid = blockIdx.x, tid = threadIdx.x;
  int jt = bid & 3, i = (bid >> 2) & (Ln - 1), b = bid >> 10;
  int j0 = jt * 64;
  int lane = tid & 63, w = tid >> 6;
  int c16 = lane & 15, quad = lane >> 4;

  const float* hsb = hs + (size_t)b * Ln * Hn;

  // A tile: As[j][k] = x_i[k] * x_j[k]  (f16), product formed in f32
  for (int idx = tid; idx < 64 * 128; idx += 256) {
    int j = idx >> 7, kk = (idx & 127) * 2;
    float2 xi = *(const float2*)(hsb + i * Hn + kk);
    float2 xj = *(const float2*)(hsb + (j0 + j) * Hn + kk);
    half2v p = {(_Float16)(xi.x * xj.x), (_Float16)(xi.y * xj.y)};
    *(half2v*)(&As[j][kk]) = p;
  }

  // acc init = a_i[h'] (already includes Wh_b)
  floatx4 acc[4][4];
#pragma unroll
  for (int ht2 = 0; ht2 < 4; ++ht2) {
    float av = a[((size_t)b * Ln + i) * Hn + w * 64 + ht2 * 16 + c16];
#pragma unroll
    for (int jt2 = 0; jt2 < 4; ++jt2) acc[jt2][ht2] = (floatx4){av, av, av, av};
  }

  // K loop: 4 chunks of 64
  for (int kc = 0; kc < 4; ++kc) {
    __syncthreads();
    const uint4* src = (const uint4*)(WmT + kc * 16384);
#pragma unroll
    for (int v = 0; v < 8; ++v) {
      int e = tid + v * 256;           // 2048 uint4 = 32 KB chunk
      int hp = e >> 3, c8 = e & 7;
      *(uint4*)((_Float16*)Ws_ + hp * 72 + c8 * 8) = src[e];
    }
    __syncthreads();
#pragma unroll
    for (int ks = 0; ks < 2; ++ks) {
      int kl = ks * 32 + quad * 8;
      half8 af[4], bfr[4];
#pragma unroll
      for (int jt2 = 0; jt2 < 4; ++jt2)
        af[jt2] = *(const half8*)(&As[jt2 * 16 + c16][kc * 64 + kl]);
#pragma unroll
      for (int ht2 = 0; ht2 < 4; ++ht2)
        bfr[ht2] = *(const half8*)(&Ws_[w * 64 + ht2 * 16 + c16][kl]);
#pragma unroll
      for (int jt2 = 0; jt2 < 4; ++jt2)
#pragma unroll
        for (int ht2 = 0; ht2 < 4; ++ht2)
          acc[jt2][ht2] = __builtin_amdgcn_mfma_f32_16x16x32_f16(
              af[jt2], bfr[ht2], acc[jt2][ht2], 0, 0, 0);
    }
  }

  // Epilogue: pre -> tanh -> x Wo (C=5), reduce over h'
  float wo[4][5];
#pragma unroll
  for (int ht2 = 0; ht2 < 4; ++ht2) {
    int hp = w * 64 + ht2 * 16 + c16;
#pragma unroll
    for (int c = 0; c < 5; ++c) wo[ht2][c] = Wo[hp * Cn + c];
  }
  const float* bvb = bvec + (size_t)b * Ln * Hn;
#pragma unroll
  for (int jt2 = 0; jt2 < 4; ++jt2) {
#pragma unroll
    for (int r = 0; r < 4; ++r) {
      int jl = jt2 * 16 + quad * 4 + r;
      int j = j0 + jl;
      int dd = j - i;
      dd = dd < -127 ? -127 : (dd > 127 ? 127 : dd);
      dd += 127;
      float s0 = 0, s1 = 0, s2 = 0, s3 = 0, s4 = 0;
#pragma unroll
      for (int ht2 = 0; ht2 < 4; ++ht2) {
        int hp = w * 64 + ht2 * 16 + c16;
        float pre = acc[jt2][ht2][r] + bvb[(size_t)j * Hn + hp] + R[dd * Hn + hp];
        float t = 1.f - 2.f / (__expf(2.f * pre) + 1.f);  // tanh, inf-safe
        s0 = fmaf(t, wo[ht2][0], s0);
        s1 = fmaf(t, wo[ht2][1], s1);
        s2 = fmaf(t, wo[ht2][2], s2);
        s3 = fmaf(t, wo[ht2][3], s3);
        s4 = fmaf(t, wo[ht2][4], s4);
      }
#pragma unroll
      for (int m = 1; m < 16; m <<= 1) {  // butterfly over the 16 h'-lanes
        s0 += __shfl_xor(s0, m);
        s1 += __shfl_xor(s1, m);
        s2 += __shfl_xor(s2, m);
        s3 += __shfl_xor(s3, m);
        s4 += __shfl_xor(s4, m);
      }
      if (c16 < 5) {
        float sv = c16 == 0 ? s0 : c16 == 1 ? s1 : c16 == 2 ? s2 : c16 == 3 ? s3 : s4;
        red[w][jl][c16] = sv;
      }
    }
  }
  __syncthreads();
  const int* mb = mask + b * Ln;
  int mi = mb[i];
  for (int idx = tid; idx < 320; idx += 256) {
    int jl = idx / 5, c = idx - jl * 5;
    int j = j0 + jl;
    float v = red[0][jl][c] + red[1][jl][c] + red[2][jl][c] + red[3][jl][c] + Wob[c];
    if (!(mi && mb[j])) v = -INFINITY;
    if (j < i) v -= 1e12f;
    out[(((size_t)b * Cn + c) * Ln + i) * Ln + j] = v;
  }
}

extern "C" void kernel_launch(void* const* d_in, const int* in_sizes, int n_in,
                              void* d_out, int out_size, void* d_ws, size_t ws_size,
                              hipStream_t stream) {
  const float* hs   = (const float*)d_in[0];
  const int*   mask = (const int*)d_in[1];
  const float* Wh_w = (const float*)d_in[2];
  const float* Wh_b = (const float*)d_in[3];
  const float* Wo_w = (const float*)d_in[4];
  const float* Wo_b = (const float*)d_in[5];
  float* out = (float*)d_out;

  char* ws = (char*)d_ws;
  float*     R    = (float*)(ws + 0);        // 255*256*4   = 261120 B
  float*     a    = (float*)(ws + 262144);   // 512*256*4   = 524288 B
  float*     bvec = (float*)(ws + 786432);   // 512*256*4   = 524288 B
  _Float16*  WmT  = (_Float16*)(ws + 1310720); // 256*256*2 = 131072 B (16B aligned)

  k_prep<<<383, 256, 0, stream>>>(hs, Wh_w, Wh_b, R, a, bvec, WmT);
  k_main<<<2048, 256, 0, stream>>>(hs, mask, R, a, bvec, WmT, Wo_w, Wo_b, out);
}

// Round 2
// 141.494 us; speedup vs baseline: 1.2921x; 1.2921x over previous
//
#include <hip/hip_runtime.h>
#include <math.h>

typedef _Float16 half8 __attribute__((ext_vector_type(8)));
typedef _Float16 half4v __attribute__((ext_vector_type(4)));
typedef float floatx4 __attribute__((ext_vector_type(4)));

union U16 { uint4 u; half8 h; };

// ---------------------------------------------------------------------------
// prep: grid 261 blocks x 256 threads
//  [0,128):   R[d][h] += table[d][kq*256..+256] @ Wh  (dg=bid>>2 8 d-rows, kq=bid&3)
//  [128,256): a/bv     += x[16 rows] @ (We+Wd / Ws-Wd) over k-slice of 64
//  [256,260): WmT2 granules: [kb*256+h] = f16 Wm[kb*8..+8][h]   (kb=k/8, k in 0..256)
//  [260]:     WoPk granules: [kb*16+c]  = f16 Wo[kb*8..+8][c]   (c<5 real, else 0)
// R/a/bv are zeroed by hipMemsetAsync before launch; accumulation via atomicAdd.
// ---------------------------------------------------------------------------
__global__ __launch_bounds__(256) void k_prep(
    const float* __restrict__ hs, const float* __restrict__ Wh,
    const float* __restrict__ Wo,
    float* __restrict__ R, float* __restrict__ a, float* __restrict__ bv,
    uint4* __restrict__ WmT2, uint4* __restrict__ WoPk)
{
  __shared__ __align__(16) char pool[32768];
  int bid = blockIdx.x, tid = threadIdx.x;

  if (bid < 128) {                       // ---- R ----
    float (*tbl)[8] = (float(*)[8])pool; // [256 k][8 d]
    int dg = bid >> 2, kq = bid & 3, d0 = dg * 8;
    for (int idx = tid; idx < 2048; idx += 256) {
      int t = idx >> 3, dl = idx & 7;
      int k = kq * 256 + t;
      float e = (float)(k & ~1) * (1.0f / 1024.f);
      float div = powf(10000.f, e);
      float ang = (float)(d0 + dl) / div;
      tbl[t][dl] = (k & 1) ? cosf(ang) : sinf(ang);
    }
    __syncthreads();
    int h = tid;
    float acc[8] = {0, 0, 0, 0, 0, 0, 0, 0};
    for (int kk = 0; kk < 256; ++kk) {
      float wv = Wh[(kq * 256 + kk) * 256 + h];
      float tr[8];
      *(float4*)&tr[0] = *(const float4*)&tbl[kk][0];
      *(float4*)&tr[4] = *(const float4*)&tbl[kk][4];
#pragma unroll
      for (int dl = 0; dl < 8; ++dl) acc[dl] = fmaf(tr[dl], wv, acc[dl]);
    }
#pragma unroll
    for (int dl = 0; dl < 8; ++dl)
      if (d0 + dl < 255) atomicAdd(&R[(d0 + dl) * 256 + h], acc[dl]);

  } else if (bid < 256) {                // ---- a / bv ----
    float (*xs)[16] = (float(*)[16])pool; // [64 k][16 r]
    int g = bid - 128, rg = g >> 2, kq = g & 3;
    int r0 = rg * 16, k0 = kq * 64;
    for (int idx = tid; idx < 1024; idx += 256) {
      int kk = idx >> 4, r = idx & 15;
      xs[kk][r] = hs[(r0 + r) * 256 + k0 + kk];
    }
    __syncthreads();
    int h = tid;
    float aa[16], bb[16];
#pragma unroll
    for (int r = 0; r < 16; ++r) { aa[r] = 0.f; bb[r] = 0.f; }
    for (int kk = 0; kk < 64; ++kk) {
      int k = k0 + kk;
      float we = Wh[k * 256 + h];
      float wsv = Wh[(256 + k) * 256 + h];
      float wd = Wh[(512 + k) * 256 + h];
      float wA = we + wd, wB = wsv - wd;
      float xr[16];
      *(float4*)&xr[0]  = *(const float4*)&xs[kk][0];
      *(float4*)&xr[4]  = *(const float4*)&xs[kk][4];
      *(float4*)&xr[8]  = *(const float4*)&xs[kk][8];
      *(float4*)&xr[12] = *(const float4*)&xs[kk][12];
#pragma unroll
      for (int r = 0; r < 16; ++r) {
        aa[r] = fmaf(xr[r], wA, aa[r]);
        bb[r] = fmaf(xr[r], wB, bb[r]);
      }
    }
#pragma unroll
    for (int r = 0; r < 16; ++r) {
      atomicAdd(&a[(r0 + r) * 256 + h], aa[r]);
      atomicAdd(&bv[(r0 + r) * 256 + h], bb[r]);
    }

  } else if (bid < 260) {                // ---- WmT2 pack ----
    _Float16 (*T)[256] = (_Float16(*)[256])pool; // [64 k][256 h]
    int q = bid - 256;
    for (int idx = tid; idx < 16384; idx += 256) {
      int k = idx >> 8, h = idx & 255;
      T[k][h] = (_Float16)Wh[(768 + q * 64 + k) * 256 + h];
    }
    __syncthreads();
    for (int gi = tid; gi < 2048; gi += 256) {
      int kbl = gi >> 8, h = gi & 255;
      U16 v;
#pragma unroll
      for (int e = 0; e < 8; ++e) v.h[e] = T[kbl * 8 + e][h];
      WmT2[(q * 8 + kbl) * 256 + h] = v.u;
    }

  } else {                               // ---- WoPk pack ----
    for (int gi = tid; gi < 512; gi += 256) {
      int kb = gi >> 4, c = gi & 15;
      U16 v;
#pragma unroll
      for (int e = 0; e < 8; ++e)
        v.h[e] = (c < 5) ? (_Float16)Wo[(kb * 8 + e) * 5 + c] : (_Float16)0.f;
      WoPk[gi] = v.u;
    }
  }
}

// ---------------------------------------------------------------------------
// main: block = (b, i, j-tile 64), 4 waves; wave w owns h' in [64w, 64w+64).
// acc init = a_i + Wh_b + bv_j + R_d (all additive C-layout constants);
// K-loop: A-frags from LDS, B-frags straight from L2 (WmT2) -> no barriers;
// epilogue: tanh -> f16 P in As -> per-wave 16j x 16c MFMA GEMM over K=256.
// ---------------------------------------------------------------------------
__global__ __launch_bounds__(256, 4) void k_main(
    const float* __restrict__ hs, const int* __restrict__ mask,
    const float* __restrict__ R, const float* __restrict__ a,
    const float* __restrict__ bvec, const float* __restrict__ Whb,
    const uint4* __restrict__ WmT2, const uint4* __restrict__ WoPk,
    const float* __restrict__ Wob, float* __restrict__ out)
{
  __shared__ __align__(16) _Float16 As[64][264]; // 33.8 KB, +8 pad (conflict-free)

  int bid = blockIdx.x, tid = threadIdx.x;
  int jt = bid & 3, i = (bid >> 2) & 255, b = bid >> 10;
  int j0 = jt * 64;
  int lane = tid & 63, w = tid >> 6;
  int c16 = lane & 15, quad = lane >> 4;
  const float* hsb = hs + (size_t)b * 65536;

  // ---- acc init: a_i + bias + bv_j + R_d (loads overlap K-loop latency) ----
  float av[4];
#pragma unroll
  for (int ht2 = 0; ht2 < 4; ++ht2) {
    int hp = 64 * w + 16 * ht2 + c16;
    av[ht2] = a[((size_t)(b * 256 + i)) * 256 + hp] + Whb[hp];
  }
  floatx4 acc[4][4];
#pragma unroll
  for (int jt2 = 0; jt2 < 4; ++jt2) {
#pragma unroll
    for (int r = 0; r < 4; ++r) {
      int jl = jt2 * 16 + quad * 4 + r;
      int jg = j0 + jl;
      int dd = jg - i;
      dd = dd < -127 ? -127 : (dd > 127 ? 127 : dd);
      dd += 127;
      const float* bp = bvec + ((size_t)(b * 256 + jg)) * 256;
      const float* rp = R + (size_t)dd * 256;
#pragma unroll
      for (int ht2 = 0; ht2 < 4; ++ht2) {
        int hp = 64 * w + 16 * ht2 + c16;
        acc[jt2][ht2][r] = av[ht2] + bp[hp] + rp[hp];
      }
    }
  }

  // ---- A tile build: As[j][k] = f16(x_i[k] * x_j[k]) ----
  for (int idx = tid; idx < 4096; idx += 256) {
    int j = idx >> 6, k4 = (idx & 63) * 4;
    float4 xi = *(const float4*)(hsb + i * 256 + k4);
    float4 xj = *(const float4*)(hsb + (j0 + j) * 256 + k4);
    half4v p = {(_Float16)(xi.x * xj.x), (_Float16)(xi.y * xj.y),
                (_Float16)(xi.z * xj.z), (_Float16)(xi.w * xj.w)};
    *(half4v*)(&As[j][k4]) = p;
  }
  __syncthreads();

  // ---- K loop: no barriers; B-frags from L2, A-frags from LDS ----
#pragma unroll 1
  for (int kc = 0; kc < 4; ++kc) {
#pragma unroll
    for (int ks = 0; ks < 2; ++ks) {
      int kb = kc * 8 + ks * 4 + quad;
      U16 bg[4];
#pragma unroll
      for (int ht2 = 0; ht2 < 4; ++ht2)
        bg[ht2].u = WmT2[kb * 256 + 64 * w + 16 * ht2 + c16];
      half8 af[4];
#pragma unroll
      for (int jt2 = 0; jt2 < 4; ++jt2)
        af[jt2] = *(const half8*)(&As[jt2 * 16 + c16][kc * 64 + ks * 32 + quad * 8]);
#pragma unroll
      for (int jt2 = 0; jt2 < 4; ++jt2)
#pragma unroll
        for (int ht2 = 0; ht2 < 4; ++ht2)
          acc[jt2][ht2] = __builtin_amdgcn_mfma_f32_16x16x32_f16(
              af[jt2], bg[ht2].h, acc[jt2][ht2], 0, 0, 0);
    }
  }

  __syncthreads();  // all A-frag reads done before P overwrites As

  // ---- Wo fragments (L2) + P = tanh(acc) into As ----
  U16 wog[8];
#pragma unroll
  for (int s = 0; s < 8; ++s) wog[s].u = WoPk[(s * 4 + quad) * 16 + c16];

#pragma unroll
  for (int jt2 = 0; jt2 < 4; ++jt2) {
#pragma unroll
    for (int ht2 = 0; ht2 < 4; ++ht2) {
      int hp = 64 * w + 16 * ht2 + c16;
#pragma unroll
      for (int r = 0; r < 4; ++r) {
        int jl = jt2 * 16 + quad * 4 + r;
        float x = acc[jt2][ht2][r];
        float t = 1.f - 2.f / (__expf(2.f * x) + 1.f); // tanh, inf-safe
        As[jl][hp] = (_Float16)t;
      }
    }
  }
  __syncthreads();

  // ---- epilogue GEMM: wave w does rows [16w,16w+16) x 16 cols, K=256 ----
  floatx4 accE = {0.f, 0.f, 0.f, 0.f};
#pragma unroll
  for (int s = 0; s < 8; ++s) {
    half8 ae = *(const half8*)(&As[16 * w + c16][s * 32 + quad * 8]);
    accE = __builtin_amdgcn_mfma_f32_16x16x32_f16(ae, wog[s].h, accE, 0, 0, 0);
  }

  const int* mb = mask + b * 256;
  int mi = mb[i];
  float wob = (c16 < 5) ? Wob[c16] : 0.f;
#pragma unroll
  for (int r = 0; r < 4; ++r) {
    int jg = j0 + 16 * w + quad * 4 + r;
    float v = accE[r] + wob;
    if (!(mi && mb[jg])) v = -INFINITY;
    if (jg < i) v -= 1e12f;
    if (c16 < 5) out[(((size_t)b * 5 + c16) * 256 + i) * 256 + jg] = v;
  }
}

extern "C" void kernel_launch(void* const* d_in, const int* in_sizes, int n_in,
                              void* d_out, int out_size, void* d_ws, size_t ws_size,
                              hipStream_t stream) {
  const float* hs   = (const float*)d_in[0];
  const int*   mask = (const int*)d_in[1];
  const float* Wh_w = (const float*)d_in[2];
  const float* Wh_b = (const float*)d_in[3];
  const float* Wo_w = (const float*)d_in[4];
  const float* Wo_b = (const float*)d_in[5];

  char* ws = (char*)d_ws;
  float* R    = (float*)(ws + 0);        // 255*256*4 = 261120 (pad to 256K)
  float* a    = (float*)(ws + 262144);   // 512*256*4 = 524288
  float* bv   = (float*)(ws + 786432);   // 512*256*4 = 524288
  uint4* WmT2 = (uint4*)(ws + 1310720);  // 256*256*2 = 131072
  uint4* WoPk = (uint4*)(ws + 1441792);  // 512*16    =   8192

  hipMemsetAsync(ws, 0, 1310720, stream);  // zero R, a, bv for atomicAdd
  k_prep<<<261, 256, 0, stream>>>(hs, Wh_w, Wo_w, R, a, bv, WmT2, WoPk);
  k_main<<<2048, 256, 0, stream>>>(hs, mask, R, a, bv, Wh_b, WmT2, WoPk, Wo_b,
                                   (float*)d_out);
}

// Round 3
// 125.372 us; speedup vs baseline: 1.4582x; 1.1286x over previous
//
#include <hip/hip_runtime.h>
#include <math.h>

typedef _Float16 half8 __attribute__((ext_vector_type(8)));
typedef _Float16 half4v __attribute__((ext_vector_type(4)));
typedef float floatx4 __attribute__((ext_vector_type(4)));

union U16 { uint4 u; half8 h; };

// ---------------------------------------------------------------------------
// prep1: 517 blocks x 256 thr. No atomics; K-split partials to ws.
//  [0,256):   R partials: dg=bid>>3 (8 d-rows), kq=bid&7 (K=128)
//             Rp[kq][(d0+dl)*256+h] = table-slice @ Wh-slice
//  [256,512): a/bv partials: rg=(bid-256)>>2 (8 rows), kq=(bid-256)&3 (K=64)
//  [512,516): WmT2 pack granules (f16)
//  [516]:     WoPk pack granules (f16)
// ---------------------------------------------------------------------------
__global__ __launch_bounds__(256) void k_prep1(
    const float* __restrict__ hs, const float* __restrict__ Wh,
    const float* __restrict__ Wo,
    float* __restrict__ Rp, float* __restrict__ ap, float* __restrict__ bp,
    uint4* __restrict__ WmT2, uint4* __restrict__ WoPk)
{
  __shared__ __align__(16) char pool[32768];
  int bid = blockIdx.x, tid = threadIdx.x;

  if (bid < 256) {                       // ---- R partials ----
    float (*tbl)[8] = (float(*)[8])pool; // [128 k][8 d]
    int dg = bid >> 3, kq = bid & 7, d0 = dg * 8, k0 = kq * 128;
    for (int idx = tid; idx < 1024; idx += 256) {
      int t = idx >> 3, dl = idx & 7;
      int k = k0 + t;
      float e = (float)(k & ~1) * (1.0f / 1024.f);
      float div = powf(10000.f, e);
      float ang = (float)(d0 + dl) / div;
      tbl[t][dl] = (k & 1) ? cosf(ang) : sinf(ang);
    }
    __syncthreads();
    int h = tid;
    float acc[8] = {0, 0, 0, 0, 0, 0, 0, 0};
    for (int kk = 0; kk < 128; ++kk) {
      float wv = Wh[(k0 + kk) * 256 + h];
      float tr[8];
      *(float4*)&tr[0] = *(const float4*)&tbl[kk][0];
      *(float4*)&tr[4] = *(const float4*)&tbl[kk][4];
#pragma unroll
      for (int dl = 0; dl < 8; ++dl) acc[dl] = fmaf(tr[dl], wv, acc[dl]);
    }
#pragma unroll
    for (int dl = 0; dl < 8; ++dl)
      Rp[kq * 65536 + (d0 + dl) * 256 + h] = acc[dl];  // d=255 row unused

  } else if (bid < 512) {                // ---- a / bv partials ----
    float (*xs)[8] = (float(*)[8])pool;  // [64 k][8 r]
    int g = bid - 256, rg = g >> 2, kq = g & 3;
    int r0 = rg * 8, k0 = kq * 64;
    for (int idx = tid; idx < 512; idx += 256) {
      int kk = idx >> 3, r = idx & 7;
      xs[kk][r] = hs[(r0 + r) * 256 + k0 + kk];
    }
    __syncthreads();
    int h = tid;
    float aa[8] = {0, 0, 0, 0, 0, 0, 0, 0}, bb[8] = {0, 0, 0, 0, 0, 0, 0, 0};
    for (int kk = 0; kk < 64; ++kk) {
      int k = k0 + kk;
      float we = Wh[k * 256 + h];
      float wsv = Wh[(256 + k) * 256 + h];
      float wd = Wh[(512 + k) * 256 + h];
      float wA = we + wd, wB = wsv - wd;
      float xr[8];
      *(float4*)&xr[0] = *(const float4*)&xs[kk][0];
      *(float4*)&xr[4] = *(const float4*)&xs[kk][4];
#pragma unroll
      for (int r = 0; r < 8; ++r) {
        aa[r] = fmaf(xr[r], wA, aa[r]);
        bb[r] = fmaf(xr[r], wB, bb[r]);
      }
    }
#pragma unroll
    for (int r = 0; r < 8; ++r) {
      ap[kq * 131072 + (r0 + r) * 256 + h] = aa[r];
      bp[kq * 131072 + (r0 + r) * 256 + h] = bb[r];
    }

  } else if (bid < 516) {                // ---- WmT2 pack ----
    _Float16 (*T)[256] = (_Float16(*)[256])pool; // [64 k][256 h]
    int q = bid - 512;
    for (int idx = tid; idx < 16384; idx += 256) {
      int k = idx >> 8, h = idx & 255;
      T[k][h] = (_Float16)Wh[(768 + q * 64 + k) * 256 + h];
    }
    __syncthreads();
    for (int gi = tid; gi < 2048; gi += 256) {
      int kbl = gi >> 8, h = gi & 255;
      U16 v;
#pragma unroll
      for (int e = 0; e < 8; ++e) v.h[e] = T[kbl * 8 + e][h];
      WmT2[(q * 8 + kbl) * 256 + h] = v.u;
    }

  } else {                               // ---- WoPk pack ----
    for (int gi = tid; gi < 512; gi += 256) {
      int kb = gi >> 4, c = gi & 15;
      U16 v;
#pragma unroll
      for (int e = 0; e < 8; ++e)
        v.h[e] = (c < 5) ? (_Float16)Wo[(kb * 8 + e) * 5 + c] : (_Float16)0.f;
      WoPk[gi] = v.u;
    }
  }
}

// ---------------------------------------------------------------------------
// prep2: 511 blocks x 256 thr — reduce the K-split partials.
//  [0,255):   R[d][h]  = sum_{kq<8} Rp
//  [255,511): rows 2*(bid-255)+{0,1}: a = sum_{kq<4} ap ; bv = sum bp
// ---------------------------------------------------------------------------
__global__ __launch_bounds__(256) void k_prep2(
    const float* __restrict__ Rp, const float* __restrict__ ap,
    const float* __restrict__ bp,
    float* __restrict__ R, float* __restrict__ a, float* __restrict__ bv)
{
  int bid = blockIdx.x, h = threadIdx.x;
  if (bid < 255) {
    int d = bid;
    float s = 0.f;
#pragma unroll
    for (int kq = 0; kq < 8; ++kq) s += Rp[kq * 65536 + d * 256 + h];
    R[d * 256 + h] = s;
  } else {
    int r0 = (bid - 255) * 2;
#pragma unroll
    for (int rr = 0; rr < 2; ++rr) {
      int r = r0 + rr;
      float sa = 0.f, sb = 0.f;
#pragma unroll
      for (int kq = 0; kq < 4; ++kq) {
        sa += ap[kq * 131072 + r * 256 + h];
        sb += bp[kq * 131072 + r * 256 + h];
      }
      a[r * 256 + h] = sa;
      bv[r * 256 + h] = sb;
    }
  }
}

// ---------------------------------------------------------------------------
// main: 4096 blocks = (b, i, j-tile 32); 4 waves, wave w owns h' [64w,64w+64)
// over all 32 j. acc init = a_i + Wh_b + bv_j + R_d. K-loop barrier-free
// (B-frags from L2). Epilogue: tanh -> f16 P in As -> waves 0,1 do the
// 16j x 16c x K=256 Wo GEMM and store.
// ---------------------------------------------------------------------------
__global__ __launch_bounds__(256, 5) void k_main(
    const float* __restrict__ hs, const int* __restrict__ mask,
    const float* __restrict__ R, const float* __restrict__ a,
    const float* __restrict__ bvec, const float* __restrict__ Whb,
    const uint4* __restrict__ WmT2, const uint4* __restrict__ WoPk,
    const float* __restrict__ Wob, float* __restrict__ out)
{
  __shared__ __align__(16) _Float16 As[32][264];  // 16.9 KB, +8 pad

  int bid = blockIdx.x, tid = threadIdx.x;
  int jt = bid & 7, i = (bid >> 3) & 255, b = bid >> 11;
  int j0 = jt * 32;
  int lane = tid & 63, w = tid >> 6;
  int c16 = lane & 15, quad = lane >> 4;
  const float* hsb = hs + (size_t)b * 65536;

  // ---- acc init: a_i + bias + bv_j + R_d ----
  float av[4];
#pragma unroll
  for (int ht2 = 0; ht2 < 4; ++ht2) {
    int hp = 64 * w + 16 * ht2 + c16;
    av[ht2] = a[((size_t)(b * 256 + i)) * 256 + hp] + Whb[hp];
  }
  floatx4 acc[2][4];
#pragma unroll
  for (int jt2 = 0; jt2 < 2; ++jt2) {
#pragma unroll
    for (int r = 0; r < 4; ++r) {
      int jl = jt2 * 16 + quad * 4 + r;
      int jg = j0 + jl;
      int dd = jg - i;
      dd = dd < -127 ? -127 : (dd > 127 ? 127 : dd);
      dd += 127;
      const float* bpr = bvec + ((size_t)(b * 256 + jg)) * 256;
      const float* rpr = R + (size_t)dd * 256;
#pragma unroll
      for (int ht2 = 0; ht2 < 4; ++ht2) {
        int hp = 64 * w + 16 * ht2 + c16;
        acc[jt2][ht2][r] = av[ht2] + bpr[hp] + rpr[hp];
      }
    }
  }

  // ---- A tile: As[j][k] = f16(x_i[k] * x_j[k]), 16B granules ----
  for (int idx = tid; idx < 1024; idx += 256) {
    int j = idx >> 5, k8 = (idx & 31) * 8;
    float4 xi0 = *(const float4*)(hsb + i * 256 + k8);
    float4 xi1 = *(const float4*)(hsb + i * 256 + k8 + 4);
    float4 xj0 = *(const float4*)(hsb + (j0 + j) * 256 + k8);
    float4 xj1 = *(const float4*)(hsb + (j0 + j) * 256 + k8 + 4);
    half8 p = {(_Float16)(xi0.x * xj0.x), (_Float16)(xi0.y * xj0.y),
               (_Float16)(xi0.z * xj0.z), (_Float16)(xi0.w * xj0.w),
               (_Float16)(xi1.x * xj1.x), (_Float16)(xi1.y * xj1.y),
               (_Float16)(xi1.z * xj1.z), (_Float16)(xi1.w * xj1.w)};
    *(half8*)(&As[j][k8]) = p;
  }
  __syncthreads();

  // ---- K loop (barrier-free): A-frags from LDS, B-frags from L2 ----
#pragma unroll 1
  for (int kc = 0; kc < 4; ++kc) {
#pragma unroll
    for (int ks = 0; ks < 2; ++ks) {
      int kb = kc * 8 + ks * 4 + quad;
      U16 bg[4];
#pragma unroll
      for (int ht2 = 0; ht2 < 4; ++ht2)
        bg[ht2].u = WmT2[kb * 256 + 64 * w + 16 * ht2 + c16];
      half8 af[2];
#pragma unroll
      for (int jt2 = 0; jt2 < 2; ++jt2)
        af[jt2] = *(const half8*)(&As[jt2 * 16 + c16][kc * 64 + ks * 32 + quad * 8]);
#pragma unroll
      for (int jt2 = 0; jt2 < 2; ++jt2)
#pragma unroll
        for (int ht2 = 0; ht2 < 4; ++ht2)
          acc[jt2][ht2] = __builtin_amdgcn_mfma_f32_16x16x32_f16(
              af[jt2], bg[ht2].h, acc[jt2][ht2], 0, 0, 0);
    }
  }

  __syncthreads();  // all A-frag reads done before P overwrites As

  // ---- P = tanh(acc) -> f16 into As ----
#pragma unroll
  for (int jt2 = 0; jt2 < 2; ++jt2) {
#pragma unroll
    for (int ht2 = 0; ht2 < 4; ++ht2) {
      int hp = 64 * w + 16 * ht2 + c16;
#pragma unroll
      for (int r = 0; r < 4; ++r) {
        int jl = jt2 * 16 + quad * 4 + r;
        float x = acc[jt2][ht2][r];
        float t = 1.f - 2.f / (__expf(2.f * x) + 1.f);  // tanh, inf-safe
        As[jl][hp] = (_Float16)t;
      }
    }
  }
  __syncthreads();

  // ---- epilogue GEMM (waves 0,1): rows [16w,16w+16) x 16c, K=256 ----
  if (w < 2) {
    U16 wog[8];
#pragma unroll
    for (int s = 0; s < 8; ++s) wog[s].u = WoPk[(s * 4 + quad) * 16 + c16];
    floatx4 accE = {0.f, 0.f, 0.f, 0.f};
#pragma unroll
    for (int s = 0; s < 8; ++s) {
      half8 ae = *(const half8*)(&As[16 * w + c16][s * 32 + quad * 8]);
      accE = __builtin_amdgcn_mfma_f32_16x16x32_f16(ae, wog[s].h, accE, 0, 0, 0);
    }
    const int* mb = mask + b * 256;
    int mi = mb[i];
    float wob = (c16 < 5) ? Wob[c16] : 0.f;
#pragma unroll
    for (int r = 0; r < 4; ++r) {
      int jg = j0 + 16 * w + quad * 4 + r;
      float v = accE[r] + wob;
      if (!(mi && mb[jg])) v = -INFINITY;
      if (jg < i) v -= 1e12f;
      if (c16 < 5) out[(((size_t)b * 5 + c16) * 256 + i) * 256 + jg] = v;
    }
  }
}

extern "C" void kernel_launch(void* const* d_in, const int* in_sizes, int n_in,
                              void* d_out, int out_size, void* d_ws, size_t ws_size,
                              hipStream_t stream) {
  const float* hs   = (const float*)d_in[0];
  const int*   mask = (const int*)d_in[1];
  const float* Wh_w = (const float*)d_in[2];
  const float* Wh_b = (const float*)d_in[3];
  const float* Wo_w = (const float*)d_in[4];
  const float* Wo_b = (const float*)d_in[5];

  char* ws = (char*)d_ws;
  float* R    = (float*)(ws + 0);        //  256*256*4  = 262144
  float* a    = (float*)(ws + 262144);   //  512*256*4  = 524288
  float* bv   = (float*)(ws + 786432);   //  512*256*4  = 524288
  uint4* WmT2 = (uint4*)(ws + 1310720);  //  256*256*2  = 131072
  uint4* WoPk = (uint4*)(ws + 1441792);  //  512*16     =   8192
  float* Rp   = (float*)(ws + 1449984);  // 8*65536*4   = 2097152
  float* ap   = (float*)(ws + 3547136);  // 4*131072*4  = 2097152
  float* bp   = (float*)(ws + 5644288);  // 4*131072*4  = 2097152  (end ~7.4MB)

  k_prep1<<<517, 256, 0, stream>>>(hs, Wh_w, Wo_w, Rp, ap, bp, WmT2, WoPk);
  k_prep2<<<511, 256, 0, stream>>>(Rp, ap, bp, R, a, bv);
  k_main<<<4096, 256, 0, stream>>>(hs, mask, R, a, bv, Wh_b, WmT2, WoPk, Wo_b,
                                   (float*)d_out);
}